// Round 6
// baseline (267.343 us; speedup 1.0000x reference)
//
#include <hip/hip_runtime.h>
#include <hip/hip_bf16.h>

#define N_IMG 32
#define CIN   128
#define INH   64
#define INW   64
#define COUT  256
#define OH    62
#define OW    62

#define IN_BLOCKS (N_IMG * 4 * 64)   // 8192
#define WT_BLOCKS (294912 / 256)     // 1152

typedef short          bf16x8 __attribute__((ext_vector_type(8)));
typedef unsigned short u16x8  __attribute__((ext_vector_type(8)));
typedef float          f32x4  __attribute__((ext_vector_type(4)));
typedef float          f32x2  __attribute__((ext_vector_type(2)));

__device__ __forceinline__ unsigned short f2bf(float x) {
    unsigned int u = __float_as_uint(x);
    u += 0x7fffu + ((u >> 16) & 1u);   // RNE
    return (unsigned short)(u >> 16);
}

__device__ __forceinline__ void gload_lds16(const void* g, void* l) {
    // global -> LDS DMA, 16 B per lane; LDS dest = wave-uniform base + lane*16
    __builtin_amdgcn_global_load_lds(
        (const __attribute__((address_space(1))) unsigned int*)g,
        (__attribute__((address_space(3))) unsigned int*)l, 16, 0, 0);
}

// Merged pre-pass: blocks [0,8192) transform input, [8192,9344) transform weights.
// TIn layout: [img][cb(4)][ih(64)][chunk(256)][8] bf16; chunk c = (iw = c>>2,
// cg = (c&3) ^ ((iw>>1)&3)) — XOR swizzle baked into the GLOBAL layout so the
// linear global_load_lds DMA lands pre-swizzled (rule #21).
// WT layout: [khw(9)][cg(16)][co(256)][i(8)] bf16, ci = cg*8 + i (A-frag order).
__global__ __launch_bounds__(256)
void transform_kernel(const float* __restrict__ In,
                      const float* __restrict__ Wsrc,
                      unsigned short* __restrict__ TIn,
                      unsigned short* __restrict__ WT) {
    if (blockIdx.x >= IN_BLOCKS) {      // ---- weight path (no barrier) ----
        int idx = (blockIdx.x - IN_BLOCKS) * 256 + threadIdx.x;   // < 294912
        int i   = idx & 7;
        int co  = (idx >> 3) & 255;
        int cgk = idx >> 11;            // khw*16 + cg
        int cg  = cgk & 15;
        int khw = cgk >> 4;             // 0..8
        int kh  = khw / 3, kw = khw - 3 * kh;
        int ci  = cg * 8 + i;
        WT[idx] = f2bf(Wsrc[co * (CIN * 9) + ci * 9 + kh * 3 + kw]);
        return;
    }
    // ---- input path: LDS-transposed, coalesced both sides ----
    __shared__ float T[32][66];           // stride 66: float2-aligned, 2-way banks max
    const int bid = blockIdx.x;           // img*256 + cb*64 + ih
    const int ih  = bid & 63;
    const int cb  = (bid >> 6) & 3;
    const int img = bid >> 8;
    {
        const int r  = threadIdx.x >> 3;
        const int c0 = (threadIdx.x & 7) * 8;
        const float* p = In + (((size_t)(img * CIN + cb * 32 + r)) * INH + ih) * INW + c0;
        f32x4 a = *(const f32x4*)p;
        f32x4 b = *(const f32x4*)(p + 4);
        *(f32x2*)&T[r][c0 + 0] = f32x2{a[0], a[1]};
        *(f32x2*)&T[r][c0 + 2] = f32x2{a[2], a[3]};
        *(f32x2*)&T[r][c0 + 4] = f32x2{b[0], b[1]};
        *(f32x2*)&T[r][c0 + 6] = f32x2{b[2], b[3]};
    }
    __syncthreads();
    const int c  = threadIdx.x;
    const int iw = c >> 2;
    const int cg = (c & 3) ^ ((iw >> 1) & 3);
    u16x8 v;
#pragma unroll
    for (int i = 0; i < 8; ++i) v[i] = f2bf(T[cg * 8 + i][iw]);
    *(u16x8*)&TIn[((size_t)bid * 256 + c) * 8] = v;
}

// One 256-thread block per (img, oh); wave w owns co in [64w, 64w+64).
// GEMM: D[m=co][n=ow] += sum_k W[co][k] * X[k][ow], k = (ci,kh,kw).
// cb-OUTER staging: 4 super-stages (ci-blocks of 32); each stages THREE input
// rows (ih = oh..oh+2) of that cb by DMA into the double buffer, then runs all
// 3 kh x 3 kw = 144 MFMA/wave before the next barrier. Same DMA bytes and weight
// traffic as the 12-stage version, but 4 barriers instead of 12: the exposed
// DMA/weight latency is paid once per 699 cyc of MFMA issue instead of per 233.
__global__ __launch_bounds__(256, 4)
void conv_mfma_bf16_kernel(const unsigned short* __restrict__ TIn,
                           const unsigned short* __restrict__ WT,
                           float* __restrict__ Out) {
    // [buf][row j(3)][2112]: per row, [0..2048) = 64 iw x 32 ci (swizzled chunks),
    // [2048..2112) zero pad (iw 64,65). DMA never touches the pad.
    __shared__ unsigned short Lin[2][3][2112];

    // Bijective XCD-chunked remap: 1984 = 8*248 -> XCD x gets images [4x, 4x+4).
    const int g   = blockIdx.x;
    const int f   = (g & 7) * 248 + (g >> 3);
    const int img = f / OH;
    const int oh  = f - img * OH;

    const int tid  = threadIdx.x;
    const int wave = tid >> 6;      // 0..3
    const int lane = tid & 63;
    const int q    = lane >> 4;     // quad 0..3
    const int ml   = lane & 15;
    const int co_base = wave * 64;

    const unsigned short* tin_base = TIn + (size_t)img * (4 * 64 * 2048);
    const bf16x8* WTv = (const bf16x8*)WT;
    const int wlane = q * 256 + co_base + ml;   // lane part of A-frag index

    // Per-lane LDS ushort offsets for B fragments (constant across stages).
    // Chunk slot for cg=q at row r is q ^ ((r>>1)&3): measured 0 bank conflicts.
    int xoff[3][4];
#pragma unroll
    for (int kw = 0; kw < 3; ++kw)
#pragma unroll
        for (int ni = 0; ni < 4; ++ni) {
            const int r = ni * 16 + ml + kw;
            xoff[kw][ni] = r * 32 + ((q ^ ((r >> 1) & 3)) << 3);
        }

    f32x4 acc[4][4];
    const f32x4 zero = {0.f, 0.f, 0.f, 0.f};
#pragma unroll
    for (int a = 0; a < 4; ++a)
#pragma unroll
        for (int b = 0; b < 4; ++b) acc[a][b] = zero;

    // Prologue: stage cb=0 rows j=0..2 into buf0; zero pad slots of all 6 row-bufs.
#pragma unroll
    for (int j = 0; j < 3; ++j)
        gload_lds16(tin_base + (oh + j) * 2048 + tid * 8, &Lin[0][j][wave * 512]);
    if (tid < 192) {
        const int rb = tid >> 5;                       // row-buffer 0..5
        ((unsigned int*)Lin)[rb * 1056 + 1024 + (tid & 31)] = 0u;
    }
    __syncthreads();   // drains DMA (vmcnt 0) + pad writes

#pragma unroll
    for (int cb = 0; cb < 4; ++cb) {
        const int cur = cb & 1;
        if (cb < 3) {   // issue next super-stage's 3 row-DMAs into the other buffer
            const unsigned short* src = tin_base + ((cb + 1) * 64 + oh) * 2048;
#pragma unroll
            for (int j = 0; j < 3; ++j)
                gload_lds16(src + j * 2048 + tid * 8, &Lin[cur ^ 1][j][wave * 512]);
        }
#pragma unroll
        for (int kh = 0; kh < 3; ++kh) {
            const unsigned short* rowb = &Lin[cur][kh][0];   // ih = oh + kh
#pragma unroll
            for (int kw = 0; kw < 3; ++kw) {
                const int khw = kh * 3 + kw;
                const bf16x8* wbase = WTv + (khw * 16 + cb * 4) * 256;  // uniform part
                bf16x8 wf[4], xf[4];
#pragma unroll
                for (int mi = 0; mi < 4; ++mi)
                    wf[mi] = wbase[wlane + mi * 16];
#pragma unroll
                for (int ni = 0; ni < 4; ++ni)
                    xf[ni] = *(const bf16x8*)&rowb[xoff[kw][ni]];
#pragma unroll
                for (int mi = 0; mi < 4; ++mi)
#pragma unroll
                    for (int ni = 0; ni < 4; ++ni)
                        acc[mi][ni] = __builtin_amdgcn_mfma_f32_16x16x32_bf16(
                            wf[mi], xf[ni], acc[mi][ni], 0, 0, 0);
            }
        }
        __syncthreads();   // vmcnt(0): next buffer landed; readers of cur done
    }

    // Epilogue: C/D layout col=lane&15, row=q*4+r (verified 16x16x32 mapping).
#pragma unroll
    for (int mi = 0; mi < 4; ++mi) {
#pragma unroll
        for (int r = 0; r < 4; ++r) {
            const int co = co_base + mi * 16 + q * 4 + r;
            float* op = Out + ((img * COUT + co) * OH + oh) * OW;
#pragma unroll
            for (int ni = 0; ni < 4; ++ni) {
                const int ow = ni * 16 + ml;
                if (ow < OW) op[ow] = acc[mi][ni][r];
            }
        }
    }
}

// ---------- mid fallback: fp32-input kernel (WT only) ----------
__global__ void wt_transform_kernel(const float* __restrict__ Wsrc,
                                    unsigned short* __restrict__ WT) {
    int idx = blockIdx.x * 256 + threadIdx.x;
    int i   = idx & 7;
    int co  = (idx >> 3) & 255;
    int cgk = idx >> 11;
    int cg  = cgk & 15;
    int khw = cgk >> 4;
    int kh  = khw / 3, kw = khw - 3 * kh;
    int ci  = cg * 8 + i;
    WT[idx] = f2bf(Wsrc[co * (CIN * 9) + ci * 9 + kh * 3 + kw]);
}

__global__ __launch_bounds__(256, 2)
void conv_mfma_fp32_kernel(const float* __restrict__ In,
                           const unsigned short* __restrict__ WT,
                           float* __restrict__ Out) {
    __shared__ unsigned short Lin[66 * 32];

    const int oh   = blockIdx.x;
    const int img  = blockIdx.y;
    const int tid  = threadIdx.x;
    const int wave = tid >> 6;
    const int lane = tid & 63;
    const int q    = lane >> 4;
    const int ml   = lane & 15;
    const int co_base = wave * 64;

    f32x4 acc[4][4];
    const f32x4 zero = {0.f, 0.f, 0.f, 0.f};
#pragma unroll
    for (int a = 0; a < 4; ++a)
#pragma unroll
        for (int b = 0; b < 4; ++b) acc[a][b] = zero;

    if (tid < 32) ((unsigned int*)&Lin[64 * 32])[tid] = 0u;

    const int s_iw = tid & 63;
    const int s_cg = tid >> 6;
    const bf16x8* WTv = (const bf16x8*)WT;

    for (int kh = 0; kh < 3; ++kh) {
        const int ih = oh + kh;
        for (int cb = 0; cb < 4; ++cb) {
            const float* p = In + (((img * CIN + cb * 32 + s_cg * 8) * INH + ih) * INW + s_iw);
            u16x8 v;
#pragma unroll
            for (int i = 0; i < 8; ++i) v[i] = f2bf(p[i * (INH * INW)]);
            __syncthreads();
            *(u16x8*)&Lin[s_iw * 32 + ((s_cg ^ (s_iw & 3)) << 3)] = v;
            __syncthreads();

#pragma unroll
            for (int kw = 0; kw < 3; ++kw) {
                const int khw = kh * 3 + kw;
                bf16x8 wf[4], xf[4];
#pragma unroll
                for (int mi = 0; mi < 4; ++mi)
                    wf[mi] = WTv[(khw * 16 + cb * 4 + q) * 256 + co_base + mi * 16 + ml];
#pragma unroll
                for (int ni = 0; ni < 4; ++ni) {
                    const int row = ni * 16 + ml + kw;
                    xf[ni] = *(const bf16x8*)&Lin[row * 32 + ((q ^ (row & 3)) << 3)];
                }
#pragma unroll
                for (int mi = 0; mi < 4; ++mi)
#pragma unroll
                    for (int ni = 0; ni < 4; ++ni)
                        acc[mi][ni] = __builtin_amdgcn_mfma_f32_16x16x32_bf16(
                            wf[mi], xf[ni], acc[mi][ni], 0, 0, 0);
            }
        }
    }

#pragma unroll
    for (int mi = 0; mi < 4; ++mi) {
#pragma unroll
        for (int r = 0; r < 4; ++r) {
            const int co = co_base + mi * 16 + q * 4 + r;
            float* op = Out + ((img * COUT + co) * OH + oh) * OW;
#pragma unroll
            for (int ni = 0; ni < 4; ++ni) {
                const int ow = ni * 16 + ml;
                if (ow < OW) op[ow] = acc[mi][ni][r];
            }
        }
    }
}

// ---------- last-resort fallback ----------
__global__ void conv_naive_kernel(const float* __restrict__ In,
                                  const float* __restrict__ Wt,
                                  float* __restrict__ Out) {
    int idx = blockIdx.x * 256 + threadIdx.x;
    const int total = N_IMG * COUT * OH * OW;
    if (idx >= total) return;
    int ow = idx % OW; int t = idx / OW;
    int oh = t % OH;   t /= OH;
    int co = t % COUT; int img = t / COUT;
    float s = 0.f;
    for (int ci = 0; ci < CIN; ++ci)
#pragma unroll
        for (int kh = 0; kh < 3; ++kh)
#pragma unroll
            for (int kw = 0; kw < 3; ++kw)
                s += In[((img * CIN + ci) * INH + oh + kh) * INW + ow + kw] *
                     Wt[co * CIN * 9 + ci * 9 + kh * 3 + kw];
    Out[idx] = s;
}

extern "C" void kernel_launch(void* const* d_in, const int* in_sizes, int n_in,
                              void* d_out, int out_size, void* d_ws, size_t ws_size,
                              hipStream_t stream) {
    const float* In   = (const float*)d_in[0];
    const float* Wsrc = (const float*)d_in[1];
    float* Out        = (float*)d_out;

    const size_t WT_BYTES  = (size_t)9 * 16 * 256 * 8 * sizeof(unsigned short);      // 589824
    const size_t TIN_BYTES = (size_t)N_IMG * 4 * 64 * 2048 * sizeof(unsigned short); // 33554432

    if (ws_size >= WT_BYTES + TIN_BYTES) {
        unsigned short* WT  = (unsigned short*)d_ws;
        unsigned short* TIn = (unsigned short*)((char*)d_ws + WT_BYTES);
        transform_kernel<<<dim3(IN_BLOCKS + WT_BLOCKS), dim3(256), 0, stream>>>(In, Wsrc, TIn, WT);
        conv_mfma_bf16_kernel<<<dim3(OH * N_IMG), dim3(256), 0, stream>>>(TIn, WT, Out);
    } else if (ws_size >= WT_BYTES) {
        unsigned short* WT = (unsigned short*)d_ws;
        wt_transform_kernel<<<dim3(WT_BLOCKS), dim3(256), 0, stream>>>(Wsrc, WT);
        conv_mfma_fp32_kernel<<<dim3(OH, N_IMG), dim3(256), 0, stream>>>(In, WT, Out);
    } else {
        const int total = N_IMG * COUT * OH * OW;
        conv_naive_kernel<<<dim3((total + 255) / 256), dim3(256), 0, stream>>>(In, Wsrc, Out);
    }
}

// Round 7
// 239.468 us; speedup vs baseline: 1.1164x; 1.1164x over previous
//
#include <hip/hip_runtime.h>
#include <hip/hip_bf16.h>

#define N_IMG 32
#define CIN   128
#define INH   64
#define INW   64
#define COUT  256
#define OH    62
#define OW    62

#define IN_BLOCKS 2048               // 32 img x 4 cb x 16 ih-groups (4 rows each)
#define WT_BLOCKS (294912 / 256)     // 1152

typedef short          bf16x8 __attribute__((ext_vector_type(8)));
typedef unsigned short u16x8  __attribute__((ext_vector_type(8)));
typedef float          f32x4  __attribute__((ext_vector_type(4)));
typedef float          f32x2  __attribute__((ext_vector_type(2)));

__device__ __forceinline__ unsigned short f2bf(float x) {
    unsigned int u = __float_as_uint(x);
    u += 0x7fffu + ((u >> 16) & 1u);   // RNE
    return (unsigned short)(u >> 16);
}

__device__ __forceinline__ void gload_lds16(const void* g, void* l) {
    // global -> LDS DMA, 16 B per lane; LDS dest = wave-uniform base + lane*16
    __builtin_amdgcn_global_load_lds(
        (const __attribute__((address_space(1))) unsigned int*)g,
        (__attribute__((address_space(3))) unsigned int*)l, 16, 0, 0);
}

// Merged pre-pass: blocks [0,2048) transform input (4 ih rows each),
// [2048, 2048+1152) transform weights.
// TIn layout: [img][cb(4)][ih(64)][chunk(256)][8] bf16; chunk c = (iw = c>>2,
// cg = (c&3) ^ ((iw>>1)&3)) — XOR swizzle baked into the GLOBAL layout so the
// linear global_load_lds DMA lands pre-swizzled (rule #21).
// WT layout: [khw(9)][cg(16)][co(256)][i(8)] bf16, ci = cg*8 + i (A-frag order).
__global__ __launch_bounds__(256)
void transform_kernel(const float* __restrict__ In,
                      const float* __restrict__ Wsrc,
                      unsigned short* __restrict__ TIn,
                      unsigned short* __restrict__ WT) {
    if (blockIdx.x >= IN_BLOCKS) {      // ---- weight path (no barriers) ----
        int idx = (blockIdx.x - IN_BLOCKS) * 256 + threadIdx.x;   // < 294912
        int i   = idx & 7;
        int co  = (idx >> 3) & 255;
        int cgk = idx >> 11;            // khw*16 + cg
        int cg  = cgk & 15;
        int khw = cgk >> 4;             // 0..8
        int kh  = khw / 3, kw = khw - 3 * kh;
        int ci  = cg * 8 + i;
        WT[idx] = f2bf(Wsrc[co * (CIN * 9) + ci * 9 + kh * 3 + kw]);
        return;
    }
    // ---- input path: LDS-transposed, coalesced both sides, 4 rows per block ----
    __shared__ float T[32][66];           // stride 66: float2-aligned, 2-way banks max
    const int bid = blockIdx.x;           // img*64 + cb*16 + ihg
    const int ih0 = (bid & 15) * 4;
    const int cb  = (bid >> 4) & 3;
    const int img = bid >> 6;

    const int r   = threadIdx.x >> 3;           // load row 0..31
    const int c0  = (threadIdx.x & 7) * 8;      // load col
    const int c   = threadIdx.x;                // store chunk
    const int iw  = c >> 2;
    const int cg  = (c & 3) ^ ((iw >> 1) & 3);

    for (int j = 0; j < 4; ++j) {
        const int ih = ih0 + j;
        const float* p = In + (((size_t)(img * CIN + cb * 32 + r)) * INH + ih) * INW + c0;
        f32x4 a = *(const f32x4*)p;
        f32x4 b = *(const f32x4*)(p + 4);
        *(f32x2*)&T[r][c0 + 0] = f32x2{a[0], a[1]};
        *(f32x2*)&T[r][c0 + 2] = f32x2{a[2], a[3]};
        *(f32x2*)&T[r][c0 + 4] = f32x2{b[0], b[1]};
        *(f32x2*)&T[r][c0 + 6] = f32x2{b[2], b[3]};
        __syncthreads();
        u16x8 v;
#pragma unroll
        for (int i = 0; i < 8; ++i) v[i] = f2bf(T[cg * 8 + i][iw]);
        *(u16x8*)&TIn[((size_t)((img * 4 + cb) * 64 + ih) * 256 + c) * 8] = v;
        if (j < 3) __syncthreads();   // T reused next iteration
    }
}

// One 256-thread block per (img, oh); wave w owns co in [64w, 64w+64).
// GEMM: D[m=co][n=ow] += sum_k W[co][k] * X[k][ow], k = (ci,kh,kw).
// 12 stages (kh x cb32), double-buffered global_load_lds staging (round-5 best
// structure). NEW: kw software-pipeline — load kw+1's weight frags while kw's
// 16 MFMA run (wcur/wnxt/xf = 48 VGPR live, fits the 64-VGPR budget), hiding
// 2 of the 3 per-stage L2 weight-latency chains under MFMA issue.
__global__ __launch_bounds__(256, 4)
void conv_mfma_bf16_kernel(const unsigned short* __restrict__ TIn,
                           const unsigned short* __restrict__ WT,
                           float* __restrict__ Out) {
    // [buf][66 rows][32 ushort]; rows 64-65 are permanent zero padding.
    __shared__ unsigned short Lin[2][2112];

    // Bijective XCD-chunked remap: 1984 = 8*248 -> XCD x gets images [4x, 4x+4).
    const int g   = blockIdx.x;
    const int f   = (g & 7) * 248 + (g >> 3);
    const int img = f / OH;
    const int oh  = f - img * OH;

    const int tid  = threadIdx.x;
    const int wave = tid >> 6;      // 0..3
    const int lane = tid & 63;
    const int q    = lane >> 4;     // quad 0..3
    const int ml   = lane & 15;
    const int co_base = wave * 64;

    const unsigned short* tin_base = TIn + (size_t)img * (4 * 64 * 2048);
    const bf16x8* WTv = (const bf16x8*)WT;
    const int wlane = q * 256 + co_base + ml;   // lane part of A-frag index

    // Per-lane LDS ushort offsets for B fragments (constant across stages).
    // Chunk slot for cg=q at row r is q ^ ((r>>1)&3): measured 0 bank conflicts.
    int xoff[3][4];
#pragma unroll
    for (int kw = 0; kw < 3; ++kw)
#pragma unroll
        for (int ni = 0; ni < 4; ++ni) {
            const int r = ni * 16 + ml + kw;
            xoff[kw][ni] = r * 32 + ((q ^ ((r >> 1) & 3)) << 3);
        }

    f32x4 acc[4][4];
    const f32x4 zero = {0.f, 0.f, 0.f, 0.f};
#pragma unroll
    for (int a = 0; a < 4; ++a)
#pragma unroll
        for (int b = 0; b < 4; ++b) acc[a][b] = zero;

    // Prologue: stage 0 into buf0 (one 16B DMA per thread) + zero pad rows.
    gload_lds16(tin_base + oh * 2048 + tid * 8, &Lin[0][wave * 512]);
    if (tid < 64) ((unsigned int*)&Lin[tid >> 5][64 * 32])[tid & 31] = 0u;
    __syncthreads();   // drains DMA (vmcnt 0) + pad writes

#pragma unroll
    for (int s = 0; s < 12; ++s) {
        const int cur = s & 1;
        if (s < 11) {   // issue next stage's DMA into the other buffer
            const int s1 = s + 1;
            const unsigned short* src =
                tin_base + ((s1 & 3) * 64 + oh + (s1 >> 2)) * 2048;
            gload_lds16(src + tid * 8, &Lin[cur ^ 1][wave * 512]);
        }
        const int kh = s >> 2, cb = s & 3;
        const bf16x8* wstage = WTv + (kh * 3 * 16 + cb * 4) * 256;  // kw stride 4096

        bf16x8 wcur[4], wnxt[4];
#pragma unroll
        for (int mi = 0; mi < 4; ++mi)                 // kw=0 weights
            wcur[mi] = wstage[wlane + mi * 16];
#pragma unroll
        for (int kw = 0; kw < 3; ++kw) {
            if (kw < 2) {                              // prefetch kw+1 weights
#pragma unroll
                for (int mi = 0; mi < 4; ++mi)
                    wnxt[mi] = wstage[(kw + 1) * 4096 + wlane + mi * 16];
            }
            bf16x8 xf[4];
#pragma unroll
            for (int ni = 0; ni < 4; ++ni)
                xf[ni] = *(const bf16x8*)&Lin[cur][xoff[kw][ni]];
#pragma unroll
            for (int mi = 0; mi < 4; ++mi)
#pragma unroll
                for (int ni = 0; ni < 4; ++ni)
                    acc[mi][ni] = __builtin_amdgcn_mfma_f32_16x16x32_bf16(
                        wcur[mi], xf[ni], acc[mi][ni], 0, 0, 0);
#pragma unroll
            for (int mi = 0; mi < 4; ++mi) wcur[mi] = wnxt[mi];   // SSA rename
        }
        __syncthreads();   // vmcnt(0): next buffer landed; readers of cur done
    }

    // Epilogue: C/D layout col=lane&15, row=q*4+r (verified 16x16x32 mapping).
#pragma unroll
    for (int mi = 0; mi < 4; ++mi) {
#pragma unroll
        for (int r = 0; r < 4; ++r) {
            const int co = co_base + mi * 16 + q * 4 + r;
            float* op = Out + ((img * COUT + co) * OH + oh) * OW;
#pragma unroll
            for (int ni = 0; ni < 4; ++ni) {
                const int ow = ni * 16 + ml;
                if (ow < OW) op[ow] = acc[mi][ni][r];
            }
        }
    }
}

// ---------- mid fallback: fp32-input kernel (WT only) ----------
__global__ void wt_transform_kernel(const float* __restrict__ Wsrc,
                                    unsigned short* __restrict__ WT) {
    int idx = blockIdx.x * 256 + threadIdx.x;
    int i   = idx & 7;
    int co  = (idx >> 3) & 255;
    int cgk = idx >> 11;
    int cg  = cgk & 15;
    int khw = cgk >> 4;
    int kh  = khw / 3, kw = khw - 3 * kh;
    int ci  = cg * 8 + i;
    WT[idx] = f2bf(Wsrc[co * (CIN * 9) + ci * 9 + kh * 3 + kw]);
}

__global__ __launch_bounds__(256, 2)
void conv_mfma_fp32_kernel(const float* __restrict__ In,
                           const unsigned short* __restrict__ WT,
                           float* __restrict__ Out) {
    __shared__ unsigned short Lin[66 * 32];

    const int oh   = blockIdx.x;
    const int img  = blockIdx.y;
    const int tid  = threadIdx.x;
    const int wave = tid >> 6;
    const int lane = tid & 63;
    const int q    = lane >> 4;
    const int ml   = lane & 15;
    const int co_base = wave * 64;

    f32x4 acc[4][4];
    const f32x4 zero = {0.f, 0.f, 0.f, 0.f};
#pragma unroll
    for (int a = 0; a < 4; ++a)
#pragma unroll
        for (int b = 0; b < 4; ++b) acc[a][b] = zero;

    if (tid < 32) ((unsigned int*)&Lin[64 * 32])[tid] = 0u;

    const int s_iw = tid & 63;
    const int s_cg = tid >> 6;
    const bf16x8* WTv = (const bf16x8*)WT;

    for (int kh = 0; kh < 3; ++kh) {
        const int ih = oh + kh;
        for (int cb = 0; cb < 4; ++cb) {
            const float* p = In + (((img * CIN + cb * 32 + s_cg * 8) * INH + ih) * INW + s_iw);
            u16x8 v;
#pragma unroll
            for (int i = 0; i < 8; ++i) v[i] = f2bf(p[i * (INH * INW)]);
            __syncthreads();
            *(u16x8*)&Lin[s_iw * 32 + ((s_cg ^ (s_iw & 3)) << 3)] = v;
            __syncthreads();

#pragma unroll
            for (int kw = 0; kw < 3; ++kw) {
                const int khw = kh * 3 + kw;
                bf16x8 wf[4], xf[4];
#pragma unroll
                for (int mi = 0; mi < 4; ++mi)
                    wf[mi] = WTv[(khw * 16 + cb * 4 + q) * 256 + co_base + mi * 16 + ml];
#pragma unroll
                for (int ni = 0; ni < 4; ++ni) {
                    const int row = ni * 16 + ml + kw;
                    xf[ni] = *(const bf16x8*)&Lin[row * 32 + ((q ^ (row & 3)) << 3)];
                }
#pragma unroll
                for (int mi = 0; mi < 4; ++mi)
#pragma unroll
                    for (int ni = 0; ni < 4; ++ni)
                        acc[mi][ni] = __builtin_amdgcn_mfma_f32_16x16x32_bf16(
                            wf[mi], xf[ni], acc[mi][ni], 0, 0, 0);
            }
        }
    }

#pragma unroll
    for (int mi = 0; mi < 4; ++mi) {
#pragma unroll
        for (int r = 0; r < 4; ++r) {
            const int co = co_base + mi * 16 + q * 4 + r;
            float* op = Out + ((img * COUT + co) * OH + oh) * OW;
#pragma unroll
            for (int ni = 0; ni < 4; ++ni) {
                const int ow = ni * 16 + ml;
                if (ow < OW) op[ow] = acc[mi][ni][r];
            }
        }
    }
}

// ---------- last-resort fallback ----------
__global__ void conv_naive_kernel(const float* __restrict__ In,
                                  const float* __restrict__ Wt,
                                  float* __restrict__ Out) {
    int idx = blockIdx.x * 256 + threadIdx.x;
    const int total = N_IMG * COUT * OH * OW;
    if (idx >= total) return;
    int ow = idx % OW; int t = idx / OW;
    int oh = t % OH;   t /= OH;
    int co = t % COUT; int img = t / COUT;
    float s = 0.f;
    for (int ci = 0; ci < CIN; ++ci)
#pragma unroll
        for (int kh = 0; kh < 3; ++kh)
#pragma unroll
            for (int kw = 0; kw < 3; ++kw)
                s += In[((img * CIN + ci) * INH + oh + kh) * INW + ow + kw] *
                     Wt[co * CIN * 9 + ci * 9 + kh * 3 + kw];
    Out[idx] = s;
}

extern "C" void kernel_launch(void* const* d_in, const int* in_sizes, int n_in,
                              void* d_out, int out_size, void* d_ws, size_t ws_size,
                              hipStream_t stream) {
    const float* In   = (const float*)d_in[0];
    const float* Wsrc = (const float*)d_in[1];
    float* Out        = (float*)d_out;

    const size_t WT_BYTES  = (size_t)9 * 16 * 256 * 8 * sizeof(unsigned short);      // 589824
    const size_t TIN_BYTES = (size_t)N_IMG * 4 * 64 * 2048 * sizeof(unsigned short); // 33554432

    if (ws_size >= WT_BYTES + TIN_BYTES) {
        unsigned short* WT  = (unsigned short*)d_ws;
        unsigned short* TIn = (unsigned short*)((char*)d_ws + WT_BYTES);
        transform_kernel<<<dim3(IN_BLOCKS + WT_BLOCKS), dim3(256), 0, stream>>>(In, Wsrc, TIn, WT);
        conv_mfma_bf16_kernel<<<dim3(OH * N_IMG), dim3(256), 0, stream>>>(TIn, WT, Out);
    } else if (ws_size >= WT_BYTES) {
        unsigned short* WT = (unsigned short*)d_ws;
        wt_transform_kernel<<<dim3(WT_BLOCKS), dim3(256), 0, stream>>>(Wsrc, WT);
        conv_mfma_fp32_kernel<<<dim3(OH, N_IMG), dim3(256), 0, stream>>>(In, WT, Out);
    } else {
        const int total = N_IMG * COUT * OH * OW;
        conv_naive_kernel<<<dim3((total + 255) / 256), dim3(256), 0, stream>>>(In, Wsrc, Out);
    }
}